// Round 8
// baseline (2612.907 us; speedup 1.0000x reference)
//
#include <hip/hip_runtime.h>

// EpisodicMemoryModule: B=128, T=512, U=256, EMB=256, 3 memory hops.
// Round 8: scores -> M=16/wave (acc 64 VGPR) + __launch_bounds__(256,4):
// 4 blocks/CU = 4 waves/SIMD to hide L2 latency on B-fragment loads
// (scores is latency-bound: 204k cy/CU measured vs ~5k cy MFMA issue).
// Scan/memupd/split pipeline frozen at R7 state (scan at structural floor).

#define DEVI static __device__ __forceinline__

typedef float f32x4 __attribute__((ext_vector_type(4)));
typedef unsigned short u16x8 __attribute__((ext_vector_type(8)));
typedef unsigned int u32x4 __attribute__((ext_vector_type(4)));
typedef __bf16 bf16x8 __attribute__((ext_vector_type(8)));

DEVI f32x4 mfma16(u16x8 a, u16x8 b, f32x4 c) {
  return __builtin_amdgcn_mfma_f32_16x16x32_bf16(
      __builtin_bit_cast(bf16x8, a), __builtin_bit_cast(bf16x8, b), c, 0, 0, 0);
}
DEVI float bf2f(unsigned short u) {
  unsigned int x = ((unsigned int)u) << 16;
  return __builtin_bit_cast(float, x);
}
DEVI float lo2f(unsigned int u) {
  unsigned int x = u << 16;
  return __builtin_bit_cast(float, x);
}
DEVI float hi2f(unsigned int u) {
  unsigned int x = u & 0xffff0000u;
  return __builtin_bit_cast(float, x);
}
DEVI unsigned short f2bf(float f) {
  unsigned int u = __builtin_bit_cast(unsigned int, f);
  return (unsigned short)((u + 0x7fffu + ((u >> 16) & 1u)) >> 16);
}
DEVI unsigned int cvtpk(float lo, float hi) {  // [bf16(lo) | bf16(hi)<<16] RTNE
  unsigned int r;
  asm("v_cvt_pk_bf16_f32 %0, %1, %2" : "=v"(r) : "v"(lo), "v"(hi));
  return r;
}
DEVI float sigmoid_f(float x) {  // inf-safe: rcp(inf)=0
  float e = __expf(-x);
  return __builtin_amdgcn_rcpf(1.f + e);
}
DEVI float tanh_f(float x) {
  float xc = fmaxf(x, -12.f);
  float e = __expf(-2.f * xc);
  return (1.f - e) * __builtin_amdgcn_rcpf(1.f + e);
}
// u-axis storage permutation: s(c) = 32*(c>>5) + 2*(c&15) + ((c>>4)&1)
DEVI int invperm(int s) { return 32 * (s >> 5) + 16 * (s & 1) + ((s & 31) >> 1); }

// ---------------- prep kernels ----------------

__global__ void cast_facts_kernel(const float* __restrict__ in,
                                  unsigned short* __restrict__ out, int n8) {
  int i = blockIdx.x * blockDim.x + threadIdx.x;
  int stride = gridDim.x * blockDim.x;
  for (; i < n8; i += stride) {
    const float4* p = (const float4*)(in + (size_t)i * 8);
    float4 a = p[0], b = p[1];
    u16x8 o;
    o[0] = f2bf(a.x); o[1] = f2bf(a.y); o[2] = f2bf(a.z); o[3] = f2bf(a.w);
    o[4] = f2bf(b.x); o[5] = f2bf(b.y); o[6] = f2bf(b.z); o[7] = f2bf(b.w);
    *(u16x8*)(out + (size_t)i * 8) = o;
  }
}

// z=0/1: wrT/whT[sv][k] = W[k][inv(sv)]  (+ permuted biases at r==0)
// z=2/3: urT/uhT[sv][sk] = U[inv(sk)][inv(sv)]
// z=4/5: l1qT/l1mT (unpermuted, EMB axis)
// z=6:   memWT[v][k] (768 k; episode segment rows permuted to match scan layout)
__global__ void prep_weights_kernel(const float* __restrict__ Wr,
                                    const float* __restrict__ Wh,
                                    const float* __restrict__ Ur,
                                    const float* __restrict__ Uh,
                                    const float* __restrict__ l1W,
                                    const float* __restrict__ br,
                                    const float* __restrict__ bh,
                                    const float* __restrict__ memW,
                                    unsigned short* __restrict__ wrT,
                                    unsigned short* __restrict__ whT,
                                    unsigned short* __restrict__ urT,
                                    unsigned short* __restrict__ uhT,
                                    unsigned short* __restrict__ l1qT,
                                    unsigned short* __restrict__ l1mT,
                                    unsigned short* __restrict__ memWT,
                                    float* __restrict__ brP,
                                    float* __restrict__ bhP) {
  int z = blockIdx.y;
  int r = blockIdx.x;   // output row (storage index for z<4, logical v for z==6)
  int c = threadIdx.x;  // 0..255
  if (z < 2) {
    const float* src = (z == 0) ? Wr : Wh;
    unsigned short* dst = (z == 0) ? wrT : whT;
    dst[r * 256 + c] = f2bf(src[c * 256 + invperm(r)]);
    if (r == 0) {
      if (z == 0) brP[c] = br[invperm(c)];
      else        bhP[c] = bh[invperm(c)];
    }
  } else if (z < 4) {
    const float* src = (z == 2) ? Ur : Uh;
    unsigned short* dst = (z == 2) ? urT : uhT;
    dst[r * 256 + c] = f2bf(src[invperm(c) * 256 + invperm(r)]);
  } else if (z < 6) {
    unsigned short* dst = (z == 4) ? l1qT : l1mT;
    for (int kk = c; kk < 512; kk += 256) {
      int srow;
      if (z == 4) srow = (kk < 256) ? kk : (kk + 256);
      else        srow = (kk < 256) ? (kk + 256) : (kk + 512);
      dst[r * 512 + kk] = f2bf(l1W[srow * 256 + r]);
    }
  } else {  // z == 6
    for (int kk = c; kk < 768; kk += 256) {
      int ksrc = (kk < 256) ? kk : (kk < 512 ? 256 + invperm(kk - 256) : kk);
      memWT[r * 768 + kk] = f2bf(memW[ksrc * 256 + r]);
    }
  }
}

__global__ void init_qm_kernel(const float* __restrict__ question,
                               unsigned short* __restrict__ qbf,
                               unsigned short* __restrict__ mbf) {
  int i = blockIdx.x * 256 + threadIdx.x;  // 32768
  unsigned short u = f2bf(question[i]);
  qbf[i] = u;
  mbf[i] = u;
}

// ---------------- xr/xh GEMM (writes interleaved [T][B][2U], storage cols) ----
__global__ __launch_bounds__(256, 2) void gemm_xrxh_kernel(
    const unsigned short* __restrict__ factsb,
    const unsigned short* __restrict__ wrT,
    const unsigned short* __restrict__ whT,
    const float* __restrict__ brP, const float* __restrict__ bhP,
    unsigned short* __restrict__ xrxh) {
  const int b = blockIdx.x >> 3;
  const int t0 = (blockIdx.x & 7) * 64;
  const int w = threadIdx.x >> 6, l = threadIdx.x & 63;
  const int l15 = l & 15, lg = l >> 4;
  const int koff = lg * 8;
  const int m0 = t0 + w * 16;

  f32x4 accR[16], accH[16];
  const f32x4 zz = {0.f, 0.f, 0.f, 0.f};
#pragma unroll
  for (int nt = 0; nt < 16; nt++) { accR[nt] = zz; accH[nt] = zz; }

  const unsigned short* arow = factsb + ((size_t)b * 512 + (m0 + l15)) * 256;
#pragma unroll
  for (int ks = 0; ks < 8; ks++) {
    u16x8 a = *(const u16x8*)&arow[ks * 32 + koff];
#pragma unroll
    for (int nt = 0; nt < 16; nt++) {
      u16x8 bwr = *(const u16x8*)&wrT[(size_t)(nt * 16 + l15) * 256 + ks * 32 + koff];
      u16x8 bwh = *(const u16x8*)&whT[(size_t)(nt * 16 + l15) * 256 + ks * 32 + koff];
      accR[nt] = mfma16(a, bwr, accR[nt]);
      accH[nt] = mfma16(a, bwh, accH[nt]);
    }
  }
#pragma unroll
  for (int nt = 0; nt < 16; nt++) {
    const int col = nt * 16 + l15;  // storage col
    const float bvr = brP[col], bvh = bhP[col];
#pragma unroll
    for (int r = 0; r < 4; r++) {
      const int t = m0 + lg * 4 + r;
      unsigned int pk = cvtpk(accR[nt][r] + bvr, accH[nt][r] + bvh);
      *(unsigned int*)&xrxh[((size_t)t * 128 + b) * 512 + col * 2] = pk;
    }
  }
}

// ---------------- attention scores GEMM (fused transforms, M=16/wave) ---------
// Grid 1024 blocks x 4 waves; 4 blocks/CU (launch_bounds(256,4)) for latency
// hiding on B-fragment L2 loads.
// SMODE 0: full K=1024 (fallback when ws too small for accQ)
// SMODE 1: q-half only (K=512: f*q@W1 + |f-q|@W3), store acc frags bf16
// SMODE 2: m-half (K=512: f*m@W2 + |f-m|@W4) + accQ frags, tanh epilogue
template <int SMODE>
__global__ __launch_bounds__(256, 4) void scores_kernel(
    const unsigned short* __restrict__ factsb,
    const unsigned short* __restrict__ l1qT,
    const unsigned short* __restrict__ l1mT,
    const float* __restrict__ l1b,
    const unsigned short* __restrict__ qbf,
    const unsigned short* __restrict__ mbf,
    const float* __restrict__ l2w, float* __restrict__ scores,
    uint2* __restrict__ accQ) {
  const int b = blockIdx.x >> 3;
  const int w = threadIdx.x >> 6, l = threadIdx.x & 63;
  const int l15 = l & 15, lg = l >> 4;
  const int koff = lg * 8;
  // block covers 64 t-rows; wave w tile at tbase+16w
  const int tbase = (blockIdx.x & 7) * 64;
  const int m0 = tbase + w * 16;
  const int fragbase = (blockIdx.x * 4 + w) * 16;  // accQ frag index base

  f32x4 acc[16];
  const f32x4 zz = {0.f, 0.f, 0.f, 0.f};
  if constexpr (SMODE == 2) {
#pragma unroll
    for (int nt = 0; nt < 16; nt++) {
      uint2 v = accQ[(size_t)(fragbase + nt) * 64 + l];
      acc[nt][0] = lo2f(v.x); acc[nt][1] = hi2f(v.x);
      acc[nt][2] = lo2f(v.y); acc[nt][3] = hi2f(v.y);
    }
  } else {
#pragma unroll
    for (int nt = 0; nt < 16; nt++) acc[nt] = zz;
  }

  const unsigned short* arow = factsb + ((size_t)b * 512 + (m0 + l15)) * 256;
  const unsigned short* qv = qbf + b * 256;
  const unsigned short* mv = mbf + b * 256;

  const int nq = (SMODE == 0) ? 4 : 2;
  for (int qi = 0; qi < nq; qi++) {
    // quarter: 0 f*q(W1) 1 f*m(W2) 2 |f-q|(W3) 3 |f-m|(W4)
    const int q2 = (SMODE == 0) ? qi : (SMODE == 1) ? 2 * qi : 2 * qi + 1;
    const unsigned short* WTs = (q2 & 1) ? l1mT : l1qT;
    const unsigned short* vvp = (q2 & 1) ? mv : qv;
    const int bko = (q2 >> 1) * 256;
    const bool isabs = (q2 >= 2);
#pragma unroll
    for (int kss = 0; kss < 8; kss++) {
      u32x4 f0 = *(const u32x4*)&arow[kss * 32 + koff];
      u32x4 vv = *(const u32x4*)&vvp[kss * 32 + koff];
      u32x4 a0;
#pragma unroll
      for (int j = 0; j < 4; j++) {  // shifted-f32 domain: bf16<<16 is exact f32
        float vl = lo2f(vv[j]), vh = hi2f(vv[j]);
        if (isabs) a0[j] = cvtpk(lo2f(f0[j]) - vl, hi2f(f0[j]) - vh) & 0x7fff7fffu;
        else       a0[j] = cvtpk(lo2f(f0[j]) * vl, hi2f(f0[j]) * vh);
      }
      u16x8 ab0 = __builtin_bit_cast(u16x8, a0);
#pragma unroll
      for (int nt = 0; nt < 16; nt++) {
        u16x8 bb = *(const u16x8*)&WTs[(size_t)(nt * 16 + l15) * 512 + bko + kss * 32 + koff];
        acc[nt] = mfma16(ab0, bb, acc[nt]);
      }
    }
  }

  if constexpr (SMODE == 1) {
#pragma unroll
    for (int nt = 0; nt < 16; nt++) {
      uint2 v;
      v.x = cvtpk(acc[nt][0], acc[nt][1]);
      v.y = cvtpk(acc[nt][2], acc[nt][3]);
      accQ[(size_t)(fragbase + nt) * 64 + l] = v;
    }
    return;
  }

  float part[4] = {0.f, 0.f, 0.f, 0.f};
#pragma unroll
  for (int nt = 0; nt < 16; nt++) {
    const int col = nt * 16 + l15;
    const float lw = l2w[col];
    const float bv = l1b[col];
#pragma unroll
    for (int r = 0; r < 4; r++) part[r] += tanh_f(acc[nt][r] + bv) * lw;
  }
#pragma unroll
  for (int m = 1; m < 16; m <<= 1)
#pragma unroll
    for (int r = 0; r < 4; r++) part[r] += __shfl_xor(part[r], m, 64);
  if (l15 == 0) {
#pragma unroll
    for (int r = 0; r < 4; r++)
      scores[(size_t)b * 512 + m0 + lg * 4 + r] = part[r];  // l2_b: softmax-invariant
  }
}

// ---------------- softmax over T per batch ----------------
__global__ void softmax_kernel(const float* __restrict__ scores,
                               float* __restrict__ att) {
  int b = blockIdx.x;
  int l = threadIdx.x;  // 64 threads, 8 scores each
  float v[8];
#pragma unroll
  for (int i = 0; i < 8; i++) v[i] = scores[b * 512 + l * 8 + i];
  float mx = v[0];
#pragma unroll
  for (int i = 1; i < 8; i++) mx = fmaxf(mx, v[i]);
#pragma unroll
  for (int m = 1; m < 64; m <<= 1) mx = fmaxf(mx, __shfl_xor(mx, m, 64));
  float s = 0.f;
#pragma unroll
  for (int i = 0; i < 8; i++) { v[i] = __expf(v[i] - mx); s += v[i]; }
#pragma unroll
  for (int m = 1; m < 64; m <<= 1) s += __shfl_xor(s, m, 64);
  float inv = __builtin_amdgcn_rcpf(s);
#pragma unroll
  for (int i = 0; i < 8; i++) att[(l * 8 + i) * 128 + b] = v[i] * inv;
}

// ---------------- attention-GRU scan + fused memory update ----------------
// 8 blocks x 512 threads (8 waves = 2/SIMD). Block = 16 batches; wave w owns
// storage cols [32w, 32w+32) as an adjacent tile pair (q=0,1). Ur/Uh fragments
// in registers. h in LDS bf16, row stride 132 dwords (==4 mod 32: 4-dword-
// aligned bank starts; odd strides double b128 conflicts — R6 lesson).
struct PF {
  uint2 x[4];  // [r]: .x = (xr|xh<<16) for q=0 col, .y = for q=1 col
  f32x4 g;
};

__global__ __launch_bounds__(512, 2) void scan_kernel(
    const unsigned short* __restrict__ xrxh,   // [T][B][2U] bf16, storage order
    const float* __restrict__ att,             // [T][B]
    const unsigned short* __restrict__ urT,    // [sv][sk] bf16
    const unsigned short* __restrict__ uhT,
    const unsigned short* __restrict__ memWT,  // [v][768] bf16 (episode rows permuted)
    const float* __restrict__ memb,
    const unsigned short* __restrict__ qbf,
    unsigned short* __restrict__ mbf,          // read old memory, write new
    float* __restrict__ memory)                // write new memory f32
{
  constexpr int PAD = 264;   // elements; 528B = 132-dword row stride (4 mod 32)
  constexpr int CPAD = 776;  // cat row stride (768+8)
  __shared__ unsigned short hlds[16 * PAD];
  __shared__ unsigned short rhlds[16 * PAD];
  __shared__ unsigned short cat[16 * CPAD];
  const int w = threadIdx.x >> 6, l = threadIdx.x & 63;
  const int l15 = l & 15, lg = l >> 4;
  const int koff = lg * 8;
  const int b0 = blockIdx.x * 16;
  const int lb = lg * 4;

  // tiles q=0,1: storage col sc = 32w + 2*l15 + q
  u16x8 urf[2][8], uhf[2][8];
#pragma unroll
  for (int q = 0; q < 2; q++) {
    const int sc = 32 * w + 2 * l15 + q;
#pragma unroll
    for (int ks = 0; ks < 8; ks++) {
      urf[q][ks] = *(const u16x8*)&urT[sc * 256 + ks * 32 + koff];
      uhf[q][ks] = *(const u16x8*)&uhT[sc * 256 + ks * 32 + koff];
    }
  }
  for (int i = threadIdx.x; i < 16 * PAD; i += 512) hlds[i] = 0;
  __syncthreads();

  const int hread = l15 * PAD + koff;
  int wdw[4], ro[4];
#pragma unroll
  for (int r = 0; r < 4; r++) {
    wdw[r] = (lb + r) * (PAD / 2) + 16 * w + l15;    // dword index in LDS
    ro[r] = (b0 + lb + r) * 512 + 64 * w + 4 * l15;  // element index in xrxh[t]
  }
  const int attoff = b0 + lb;

  float hc[2][4];
#pragma unroll
  for (int q = 0; q < 2; q++)
#pragma unroll
    for (int r = 0; r < 4; r++) hc[q][r] = 0.f;

  const f32x4 zz = {0.f, 0.f, 0.f, 0.f};

  auto prefetch = [&](int t) {
    PF pf;
    const unsigned short* xb = xrxh + (size_t)t * 65536;
#pragma unroll
    for (int r = 0; r < 4; r++) pf.x[r] = *(const uint2*)&xb[ro[r]];
    pf.g = *(const f32x4*)&att[t * 128 + attoff];
    return pf;
  };

  auto step = [&](const PF& pf) {
    u16x8 hf[8];
#pragma unroll
    for (int ks = 0; ks < 8; ks++)
      hf[ks] = *(const u16x8*)&hlds[hread + ks * 32];
    f32x4 aA[2] = {zz, zz}, aB[2] = {zz, zz};
#pragma unroll
    for (int ks = 0; ks < 4; ks++)
#pragma unroll
      for (int q = 0; q < 2; q++) {
        aA[q] = mfma16(hf[ks], urf[q][ks], aA[q]);
        aB[q] = mfma16(hf[ks + 4], urf[q][ks + 4], aB[q]);
      }
#pragma unroll
    for (int r = 0; r < 4; r++) {
      const uint2 xv = pf.x[r];
      float s0 = aA[0][r] + aB[0][r] + lo2f(xv.x);
      float s1 = aA[1][r] + aB[1][r] + lo2f(xv.y);
      float rh0 = sigmoid_f(s0) * hc[0][r];
      float rh1 = sigmoid_f(s1) * hc[1][r];
      ((unsigned int*)rhlds)[wdw[r]] = cvtpk(rh0, rh1);
    }
    __syncthreads();
    u16x8 rf[8];
#pragma unroll
    for (int ks = 0; ks < 8; ks++)
      rf[ks] = *(const u16x8*)&rhlds[hread + ks * 32];
    f32x4 bA[2] = {zz, zz}, bB[2] = {zz, zz};
#pragma unroll
    for (int ks = 0; ks < 4; ks++)
#pragma unroll
      for (int q = 0; q < 2; q++) {
        bA[q] = mfma16(rf[ks], uhf[q][ks], bA[q]);
        bB[q] = mfma16(rf[ks + 4], uhf[q][ks + 4], bB[q]);
      }
#pragma unroll
    for (int r = 0; r < 4; r++) {
      const uint2 xv = pf.x[r];
      float ht0 = tanh_f(bA[0][r] + bB[0][r] + hi2f(xv.x));
      float ht1 = tanh_f(bA[1][r] + bB[1][r] + hi2f(xv.y));
      const float g = pf.g[r];
      hc[0][r] = fmaf(g, ht0 - hc[0][r], hc[0][r]);
      hc[1][r] = fmaf(g, ht1 - hc[1][r], hc[1][r]);
      ((unsigned int*)hlds)[wdw[r]] = cvtpk(hc[0][r], hc[1][r]);
    }
    __syncthreads();
  };

  PF cur = prefetch(0);
#pragma unroll 2
  for (int t = 0; t < 512; t++) {
    PF nxt = prefetch(t + 1);  // t=511 reads adjacent ws (allocated, unused)
    step(cur);
    cur = nxt;
  }

  // ===== fused memory update =====
  // cat[16][CPAD]: [0:256) memory (logical), [256:512) episode (storage order),
  //                [512:768) question (logical)
  {
    const int i = (int)threadIdx.x;  // 512 threads: one u16x8 each for mem & q
    const int bb = i >> 5, cc = (i & 31) * 8;
    *(u16x8*)&cat[bb * CPAD + cc] = *(const u16x8*)&mbf[(b0 + bb) * 256 + cc];
    *(u16x8*)&cat[bb * CPAD + 512 + cc] = *(const u16x8*)&qbf[(b0 + bb) * 256 + cc];
  }
#pragma unroll
  for (int r = 0; r < 4; r++) {
    *(unsigned int*)&cat[(lb + r) * CPAD + 256 + 32 * w + 2 * l15] =
        cvtpk(hc[0][r], hc[1][r]);
  }
  __syncthreads();

  f32x4 mA[2] = {zz, zz}, mB[2] = {zz, zz};
#pragma unroll
  for (int ks = 0; ks < 24; ks += 2) {
    u16x8 a0 = *(const u16x8*)&cat[l15 * CPAD + ks * 32 + koff];
    u16x8 a1 = *(const u16x8*)&cat[l15 * CPAD + (ks + 1) * 32 + koff];
#pragma unroll
    for (int q = 0; q < 2; q++) {
      const int vrow = (2 * w + q) * 16 + l15;
      u16x8 bf0 = *(const u16x8*)&memWT[(size_t)vrow * 768 + ks * 32 + koff];
      u16x8 bf1 = *(const u16x8*)&memWT[(size_t)vrow * 768 + (ks + 1) * 32 + koff];
      mA[q] = mfma16(a0, bf0, mA[q]);
      mB[q] = mfma16(a1, bf1, mB[q]);
    }
  }
#pragma unroll
  for (int q = 0; q < 2; q++) {
    const int col = (2 * w + q) * 16 + l15;  // logical v
    const float bv = memb[col];
#pragma unroll
    for (int r = 0; r < 4; r++) {
      float v = fmaxf(mA[q][r] + mB[q][r] + bv, 0.f);
      memory[(size_t)(b0 + lb + r) * 256 + col] = v;
      mbf[(size_t)(b0 + lb + r) * 256 + col] = f2bf(v);
    }
  }
}

__global__ void writeout_kernel(const float* __restrict__ memory,
                                const float* __restrict__ question,
                                float* __restrict__ out) {
  int i = blockIdx.x * 256 + threadIdx.x;  // 65536
  int b = i >> 9, c = i & 511;
  out[i] = (c < 256) ? memory[b * 256 + c] : question[b * 256 + (c - 256)];
}

// ---------------- launch ----------------
extern "C" void kernel_launch(void* const* d_in, const int* in_sizes, int n_in,
                              void* d_out, int out_size, void* d_ws, size_t ws_size,
                              hipStream_t stream) {
  (void)in_sizes; (void)n_in; (void)out_size;
  const float* facts = (const float*)d_in[0];
  const float* question = (const float*)d_in[1];
  const float* l1W = (const float*)d_in[2];
  const float* l1b = (const float*)d_in[3];
  const float* l2W = (const float*)d_in[4];
  const float* Wr = (const float*)d_in[6];
  const float* Ur = (const float*)d_in[7];
  const float* br = (const float*)d_in[8];
  const float* Wh = (const float*)d_in[9];
  const float* Uh = (const float*)d_in[10];
  const float* bh = (const float*)d_in[11];
  const float* memW = (const float*)d_in[12];
  const float* memb = (const float*)d_in[13];
  float* out = (float*)d_out;

  char* ws = (char*)d_ws;
  unsigned short* factsb = (unsigned short*)(ws + 0);          // 33,554,432 B
  unsigned short* xrxh   = (unsigned short*)(ws + 33554432);   // 67,108,864 B [T][B][2U]
  unsigned short* wrT    = (unsigned short*)(ws + 100663296);  // 131,072 B
  unsigned short* whT    = (unsigned short*)(ws + 100794368);
  unsigned short* urT    = (unsigned short*)(ws + 100925440);
  unsigned short* uhT    = (unsigned short*)(ws + 101056512);
  unsigned short* l1qT   = (unsigned short*)(ws + 101187584);  // 524,288 B
  unsigned short* l1mT   = (unsigned short*)(ws + 101711872);  // 524,288 B
  unsigned short* qbf    = (unsigned short*)(ws + 102236160);  // 65,536 B
  unsigned short* mbf    = (unsigned short*)(ws + 102301696);  // 65,536 B
  float* scores          = (float*)(ws + 102367232);           // 262,144 B
  float* att             = (float*)(ws + 102629376);           // 262,144 B
  float* memory          = (float*)(ws + 102891520);           // 131,072 B
  float* brP             = (float*)(ws + 103022592);           // 1,024 B
  float* bhP             = (float*)(ws + 103023616);           // 1,024 B
  unsigned short* memWT  = (unsigned short*)(ws + 103024640);  // 393,216 B
  uint2* accQ            = (uint2*)(ws + 103417856);           // 33,554,432 B
  const bool split = ws_size >= 103417856ull + 33554432ull;    // 136,972,288 B

  cast_facts_kernel<<<2048, 256, 0, stream>>>(facts, factsb, 2097152);
  prep_weights_kernel<<<dim3(256, 7), 256, 0, stream>>>(
      Wr, Wh, Ur, Uh, l1W, br, bh, memW,
      wrT, whT, urT, uhT, l1qT, l1mT, memWT, brP, bhP);
  init_qm_kernel<<<128, 256, 0, stream>>>(question, qbf, mbf);

  gemm_xrxh_kernel<<<1024, 256, 0, stream>>>(factsb, wrT, whT, brP, bhP, xrxh);
  if (split)
    scores_kernel<1><<<1024, 256, 0, stream>>>(factsb, l1qT, l1mT, l1b, qbf, mbf,
                                               l2W, scores, accQ);

  for (int step = 0; step < 3; step++) {
    if (split)
      scores_kernel<2><<<1024, 256, 0, stream>>>(factsb, l1qT, l1mT, l1b, qbf, mbf,
                                                 l2W, scores, accQ);
    else
      scores_kernel<0><<<1024, 256, 0, stream>>>(factsb, l1qT, l1mT, l1b, qbf, mbf,
                                                 l2W, scores, accQ);
    softmax_kernel<<<128, 64, 0, stream>>>(scores, att);
    scan_kernel<<<8, 512, 0, stream>>>(xrxh, att, urT, uhT, memWT, memb, qbf, mbf, memory);
  }
  writeout_kernel<<<256, 256, 0, stream>>>(memory, question, out);
}

// Round 9
// 2243.568 us; speedup vs baseline: 1.1646x; 1.1646x over previous
//
#include <hip/hip_runtime.h>

// EpisodicMemoryModule: B=128, T=512, U=256, EMB=256, 3 memory hops.
// Round 9: scores B-fragments staged in LDS once per block (4 waves shared) —
// R8 proved scores is L2->CU BW-bound (10 B/cy/CU on scattered b128); staging
// cuts per-CU traffic 4x and makes global reads contiguous. M=32/wave (R7).
// Scan/memupd/split frozen at R7 state (scan at structural floor, 640 us).

#define DEVI static __device__ __forceinline__

typedef float f32x4 __attribute__((ext_vector_type(4)));
typedef unsigned short u16x8 __attribute__((ext_vector_type(8)));
typedef unsigned int u32x4 __attribute__((ext_vector_type(4)));
typedef __bf16 bf16x8 __attribute__((ext_vector_type(8)));

DEVI f32x4 mfma16(u16x8 a, u16x8 b, f32x4 c) {
  return __builtin_amdgcn_mfma_f32_16x16x32_bf16(
      __builtin_bit_cast(bf16x8, a), __builtin_bit_cast(bf16x8, b), c, 0, 0, 0);
}
DEVI float bf2f(unsigned short u) {
  unsigned int x = ((unsigned int)u) << 16;
  return __builtin_bit_cast(float, x);
}
DEVI float lo2f(unsigned int u) {
  unsigned int x = u << 16;
  return __builtin_bit_cast(float, x);
}
DEVI float hi2f(unsigned int u) {
  unsigned int x = u & 0xffff0000u;
  return __builtin_bit_cast(float, x);
}
DEVI unsigned short f2bf(float f) {
  unsigned int u = __builtin_bit_cast(unsigned int, f);
  return (unsigned short)((u + 0x7fffu + ((u >> 16) & 1u)) >> 16);
}
DEVI unsigned int cvtpk(float lo, float hi) {  // [bf16(lo) | bf16(hi)<<16] RTNE
  unsigned int r;
  asm("v_cvt_pk_bf16_f32 %0, %1, %2" : "=v"(r) : "v"(lo), "v"(hi));
  return r;
}
DEVI float sigmoid_f(float x) {  // inf-safe: rcp(inf)=0
  float e = __expf(-x);
  return __builtin_amdgcn_rcpf(1.f + e);
}
DEVI float tanh_f(float x) {
  float xc = fmaxf(x, -12.f);
  float e = __expf(-2.f * xc);
  return (1.f - e) * __builtin_amdgcn_rcpf(1.f + e);
}
// u-axis storage permutation: s(c) = 32*(c>>5) + 2*(c&15) + ((c>>4)&1)
DEVI int invperm(int s) { return 32 * (s >> 5) + 16 * (s & 1) + ((s & 31) >> 1); }

// ---------------- prep kernels ----------------

__global__ void cast_facts_kernel(const float* __restrict__ in,
                                  unsigned short* __restrict__ out, int n8) {
  int i = blockIdx.x * blockDim.x + threadIdx.x;
  int stride = gridDim.x * blockDim.x;
  for (; i < n8; i += stride) {
    const float4* p = (const float4*)(in + (size_t)i * 8);
    float4 a = p[0], b = p[1];
    u16x8 o;
    o[0] = f2bf(a.x); o[1] = f2bf(a.y); o[2] = f2bf(a.z); o[3] = f2bf(a.w);
    o[4] = f2bf(b.x); o[5] = f2bf(b.y); o[6] = f2bf(b.z); o[7] = f2bf(b.w);
    *(u16x8*)(out + (size_t)i * 8) = o;
  }
}

// z=0/1: wrT/whT[sv][k] = W[k][inv(sv)]  (+ permuted biases at r==0)
// z=2/3: urT/uhT[sv][sk] = U[inv(sk)][inv(sv)]
// z=4/5: l1qT/l1mT (unpermuted, EMB axis)
// z=6:   memWT[v][k] (768 k; episode segment rows permuted to match scan layout)
__global__ void prep_weights_kernel(const float* __restrict__ Wr,
                                    const float* __restrict__ Wh,
                                    const float* __restrict__ Ur,
                                    const float* __restrict__ Uh,
                                    const float* __restrict__ l1W,
                                    const float* __restrict__ br,
                                    const float* __restrict__ bh,
                                    const float* __restrict__ memW,
                                    unsigned short* __restrict__ wrT,
                                    unsigned short* __restrict__ whT,
                                    unsigned short* __restrict__ urT,
                                    unsigned short* __restrict__ uhT,
                                    unsigned short* __restrict__ l1qT,
                                    unsigned short* __restrict__ l1mT,
                                    unsigned short* __restrict__ memWT,
                                    float* __restrict__ brP,
                                    float* __restrict__ bhP) {
  int z = blockIdx.y;
  int r = blockIdx.x;   // output row (storage index for z<4, logical v for z==6)
  int c = threadIdx.x;  // 0..255
  if (z < 2) {
    const float* src = (z == 0) ? Wr : Wh;
    unsigned short* dst = (z == 0) ? wrT : whT;
    dst[r * 256 + c] = f2bf(src[c * 256 + invperm(r)]);
    if (r == 0) {
      if (z == 0) brP[c] = br[invperm(c)];
      else        bhP[c] = bh[invperm(c)];
    }
  } else if (z < 4) {
    const float* src = (z == 2) ? Ur : Uh;
    unsigned short* dst = (z == 2) ? urT : uhT;
    dst[r * 256 + c] = f2bf(src[invperm(c) * 256 + invperm(r)]);
  } else if (z < 6) {
    unsigned short* dst = (z == 4) ? l1qT : l1mT;
    for (int kk = c; kk < 512; kk += 256) {
      int srow;
      if (z == 4) srow = (kk < 256) ? kk : (kk + 256);
      else        srow = (kk < 256) ? (kk + 256) : (kk + 512);
      dst[r * 512 + kk] = f2bf(l1W[srow * 256 + r]);
    }
  } else {  // z == 6
    for (int kk = c; kk < 768; kk += 256) {
      int ksrc = (kk < 256) ? kk : (kk < 512 ? 256 + invperm(kk - 256) : kk);
      memWT[r * 768 + kk] = f2bf(memW[ksrc * 256 + r]);
    }
  }
}

__global__ void init_qm_kernel(const float* __restrict__ question,
                               unsigned short* __restrict__ qbf,
                               unsigned short* __restrict__ mbf) {
  int i = blockIdx.x * 256 + threadIdx.x;  // 32768
  unsigned short u = f2bf(question[i]);
  qbf[i] = u;
  mbf[i] = u;
}

// ---------------- xr/xh GEMM (writes interleaved [T][B][2U], storage cols) ----
__global__ __launch_bounds__(256, 2) void gemm_xrxh_kernel(
    const unsigned short* __restrict__ factsb,
    const unsigned short* __restrict__ wrT,
    const unsigned short* __restrict__ whT,
    const float* __restrict__ brP, const float* __restrict__ bhP,
    unsigned short* __restrict__ xrxh) {
  const int b = blockIdx.x >> 3;
  const int t0 = (blockIdx.x & 7) * 64;
  const int w = threadIdx.x >> 6, l = threadIdx.x & 63;
  const int l15 = l & 15, lg = l >> 4;
  const int koff = lg * 8;
  const int m0 = t0 + w * 16;

  f32x4 accR[16], accH[16];
  const f32x4 zz = {0.f, 0.f, 0.f, 0.f};
#pragma unroll
  for (int nt = 0; nt < 16; nt++) { accR[nt] = zz; accH[nt] = zz; }

  const unsigned short* arow = factsb + ((size_t)b * 512 + (m0 + l15)) * 256;
#pragma unroll
  for (int ks = 0; ks < 8; ks++) {
    u16x8 a = *(const u16x8*)&arow[ks * 32 + koff];
#pragma unroll
    for (int nt = 0; nt < 16; nt++) {
      u16x8 bwr = *(const u16x8*)&wrT[(size_t)(nt * 16 + l15) * 256 + ks * 32 + koff];
      u16x8 bwh = *(const u16x8*)&whT[(size_t)(nt * 16 + l15) * 256 + ks * 32 + koff];
      accR[nt] = mfma16(a, bwr, accR[nt]);
      accH[nt] = mfma16(a, bwh, accH[nt]);
    }
  }
#pragma unroll
  for (int nt = 0; nt < 16; nt++) {
    const int col = nt * 16 + l15;  // storage col
    const float bvr = brP[col], bvh = bhP[col];
#pragma unroll
    for (int r = 0; r < 4; r++) {
      const int t = m0 + lg * 4 + r;
      unsigned int pk = cvtpk(accR[nt][r] + bvr, accH[nt][r] + bvh);
      *(unsigned int*)&xrxh[((size_t)t * 128 + b) * 512 + col * 2] = pk;
    }
  }
}

// ---------------- attention scores GEMM (LDS-staged B, M=32/wave) -------------
// Block = 4 waves sharing LDS-staged B chunks [256 e][128 k] (pad stride 144).
// SMODE 0: full K=1024 (8 chunks, fallback). SMODE 1: q-half (4 chunks over
// l1qT), store acc frags bf16. SMODE 2: m-half (l1mT) + accQ, tanh epilogue.
template <int SMODE>
__global__ __launch_bounds__(256, 2) void scores_kernel(
    const unsigned short* __restrict__ factsb,
    const unsigned short* __restrict__ l1qT,
    const unsigned short* __restrict__ l1mT,
    const float* __restrict__ l1b,
    const unsigned short* __restrict__ qbf,
    const unsigned short* __restrict__ mbf,
    const float* __restrict__ l2w, float* __restrict__ scores,
    uint2* __restrict__ accQ) {
  __shared__ unsigned short bstg[256][144];  // 73,728 B; stride 36 dw (4 mod 32)
  const int b = blockIdx.x >> 2;
  const int w = threadIdx.x >> 6, l = threadIdx.x & 63;
  const int l15 = l & 15, lg = l >> 4;
  const int koff = lg * 8;
  const int tbase = (blockIdx.x & 3) * 128;
  const int m0 = tbase + w * 16;
  const int fragbase = ((blockIdx.x * 4 + w) * 2) * 16;  // accQ frag index base
  const int srow = threadIdx.x >> 4;          // staging row within 16-row group
  const int scol = (threadIdx.x & 15) * 8;    // staging col (8 u16 = 16 B)

  f32x4 acc[2][16];
  const f32x4 zz = {0.f, 0.f, 0.f, 0.f};
  if constexpr (SMODE == 2) {
#pragma unroll
    for (int s = 0; s < 2; s++)
#pragma unroll
      for (int nt = 0; nt < 16; nt++) {
        uint2 v = accQ[(size_t)(fragbase + s * 16 + nt) * 64 + l];
        acc[s][nt][0] = lo2f(v.x); acc[s][nt][1] = hi2f(v.x);
        acc[s][nt][2] = lo2f(v.y); acc[s][nt][3] = hi2f(v.y);
      }
  } else {
#pragma unroll
    for (int s = 0; s < 2; s++)
#pragma unroll
      for (int nt = 0; nt < 16; nt++) acc[s][nt] = zz;
  }

  const unsigned short* arow0 = factsb + ((size_t)b * 512 + (m0 + l15)) * 256;
  const unsigned short* arow1 = arow0 + 64 * 256;
  const unsigned short* qv = qbf + b * 256;
  const unsigned short* mv = mbf + b * 256;

  const int nc = (SMODE == 0) ? 8 : 4;
#pragma unroll
  for (int c = 0; c < 8; c++) {
    if (c >= nc) break;
    // chunk -> WT selection / transform
    const unsigned short* WTs =
        (SMODE == 1) ? l1qT : (SMODE == 2) ? l1mT : ((c < 4) ? l1qT : l1mT);
    const unsigned short* vvp =
        (SMODE == 1) ? qv : (SMODE == 2) ? mv : ((c < 4) ? qv : mv);
    const int cc = c & 3;                 // col chunk within WT: cols [cc*128,..)
    const bool isabs = (cc >= 2);         // cols >= 256 are the |f-v| quarters
    const unsigned short* WTc = WTs + cc * 128;

    __syncthreads();  // all waves done reading previous chunk
#pragma unroll
    for (int p = 0; p < 16; p++) {        // stage [256][128]: coalesced 16B/lane
      const int row = p * 16 + srow;
      *(u16x8*)&bstg[row][scol] = *(const u16x8*)&WTc[(size_t)row * 512 + scol];
    }
    __syncthreads();

#pragma unroll
    for (int j = 0; j < 4; j++) {
      const int kss = (cc & 1) * 4 + j;   // facts k-group for this chunk col set
      u32x4 f0 = *(const u32x4*)&arow0[kss * 32 + koff];
      u32x4 f1 = *(const u32x4*)&arow1[kss * 32 + koff];
      u32x4 vv = *(const u32x4*)&vvp[kss * 32 + koff];
      u32x4 a0, a1;
#pragma unroll
      for (int jj = 0; jj < 4; jj++) {    // shifted-f32: bf16<<16 is exact f32
        float vl = lo2f(vv[jj]), vh = hi2f(vv[jj]);
        if (isabs) {
          a0[jj] = cvtpk(lo2f(f0[jj]) - vl, hi2f(f0[jj]) - vh) & 0x7fff7fffu;
          a1[jj] = cvtpk(lo2f(f1[jj]) - vl, hi2f(f1[jj]) - vh) & 0x7fff7fffu;
        } else {
          a0[jj] = cvtpk(lo2f(f0[jj]) * vl, hi2f(f0[jj]) * vh);
          a1[jj] = cvtpk(lo2f(f1[jj]) * vl, hi2f(f1[jj]) * vh);
        }
      }
      u16x8 ab0 = __builtin_bit_cast(u16x8, a0);
      u16x8 ab1 = __builtin_bit_cast(u16x8, a1);
#pragma unroll
      for (int nt = 0; nt < 16; nt++) {
        u16x8 bb = *(const u16x8*)&bstg[nt * 16 + l15][j * 32 + koff];
        acc[0][nt] = mfma16(ab0, bb, acc[0][nt]);
        acc[1][nt] = mfma16(ab1, bb, acc[1][nt]);
      }
    }
  }

  if constexpr (SMODE == 1) {
#pragma unroll
    for (int s = 0; s < 2; s++)
#pragma unroll
      for (int nt = 0; nt < 16; nt++) {
        uint2 v;
        v.x = cvtpk(acc[s][nt][0], acc[s][nt][1]);
        v.y = cvtpk(acc[s][nt][2], acc[s][nt][3]);
        accQ[(size_t)(fragbase + s * 16 + nt) * 64 + l] = v;
      }
    return;
  }

  float part[2][4] = {{0.f, 0.f, 0.f, 0.f}, {0.f, 0.f, 0.f, 0.f}};
#pragma unroll
  for (int nt = 0; nt < 16; nt++) {
    const int col = nt * 16 + l15;
    const float lw = l2w[col];
    const float bv = l1b[col];
#pragma unroll
    for (int s = 0; s < 2; s++)
#pragma unroll
      for (int r = 0; r < 4; r++) part[s][r] += tanh_f(acc[s][nt][r] + bv) * lw;
  }
#pragma unroll
  for (int m = 1; m < 16; m <<= 1)
#pragma unroll
    for (int s = 0; s < 2; s++)
#pragma unroll
      for (int r = 0; r < 4; r++) part[s][r] += __shfl_xor(part[s][r], m, 64);
  if (l15 == 0) {
#pragma unroll
    for (int s = 0; s < 2; s++)
#pragma unroll
      for (int r = 0; r < 4; r++)
        scores[(size_t)b * 512 + m0 + s * 64 + lg * 4 + r] = part[s][r];
  }
}

// ---------------- softmax over T per batch ----------------
__global__ void softmax_kernel(const float* __restrict__ scores,
                               float* __restrict__ att) {
  int b = blockIdx.x;
  int l = threadIdx.x;  // 64 threads, 8 scores each
  float v[8];
#pragma unroll
  for (int i = 0; i < 8; i++) v[i] = scores[b * 512 + l * 8 + i];
  float mx = v[0];
#pragma unroll
  for (int i = 1; i < 8; i++) mx = fmaxf(mx, v[i]);
#pragma unroll
  for (int m = 1; m < 64; m <<= 1) mx = fmaxf(mx, __shfl_xor(mx, m, 64));
  float s = 0.f;
#pragma unroll
  for (int i = 0; i < 8; i++) { v[i] = __expf(v[i] - mx); s += v[i]; }
#pragma unroll
  for (int m = 1; m < 64; m <<= 1) s += __shfl_xor(s, m, 64);
  float inv = __builtin_amdgcn_rcpf(s);
#pragma unroll
  for (int i = 0; i < 8; i++) att[(l * 8 + i) * 128 + b] = v[i] * inv;
}

// ---------------- attention-GRU scan + fused memory update ----------------
// 8 blocks x 512 threads (8 waves = 2/SIMD). Block = 16 batches; wave w owns
// storage cols [32w, 32w+32) as an adjacent tile pair (q=0,1). Ur/Uh fragments
// in registers. h in LDS bf16, row stride 132 dwords (==4 mod 32: 4-dword-
// aligned bank starts; odd strides double b128 conflicts — R6 lesson).
struct PF {
  uint2 x[4];  // [r]: .x = (xr|xh<<16) for q=0 col, .y = for q=1 col
  f32x4 g;
};

__global__ __launch_bounds__(512, 2) void scan_kernel(
    const unsigned short* __restrict__ xrxh,   // [T][B][2U] bf16, storage order
    const float* __restrict__ att,             // [T][B]
    const unsigned short* __restrict__ urT,    // [sv][sk] bf16
    const unsigned short* __restrict__ uhT,
    const unsigned short* __restrict__ memWT,  // [v][768] bf16 (episode rows permuted)
    const float* __restrict__ memb,
    const unsigned short* __restrict__ qbf,
    unsigned short* __restrict__ mbf,          // read old memory, write new
    float* __restrict__ memory)                // write new memory f32
{
  constexpr int PAD = 264;   // elements; 528B = 132-dword row stride (4 mod 32)
  constexpr int CPAD = 776;  // cat row stride (768+8)
  __shared__ unsigned short hlds[16 * PAD];
  __shared__ unsigned short rhlds[16 * PAD];
  __shared__ unsigned short cat[16 * CPAD];
  const int w = threadIdx.x >> 6, l = threadIdx.x & 63;
  const int l15 = l & 15, lg = l >> 4;
  const int koff = lg * 8;
  const int b0 = blockIdx.x * 16;
  const int lb = lg * 4;

  // tiles q=0,1: storage col sc = 32w + 2*l15 + q
  u16x8 urf[2][8], uhf[2][8];
#pragma unroll
  for (int q = 0; q < 2; q++) {
    const int sc = 32 * w + 2 * l15 + q;
#pragma unroll
    for (int ks = 0; ks < 8; ks++) {
      urf[q][ks] = *(const u16x8*)&urT[sc * 256 + ks * 32 + koff];
      uhf[q][ks] = *(const u16x8*)&uhT[sc * 256 + ks * 32 + koff];
    }
  }
  for (int i = threadIdx.x; i < 16 * PAD; i += 512) hlds[i] = 0;
  __syncthreads();

  const int hread = l15 * PAD + koff;
  int wdw[4], ro[4];
#pragma unroll
  for (int r = 0; r < 4; r++) {
    wdw[r] = (lb + r) * (PAD / 2) + 16 * w + l15;    // dword index in LDS
    ro[r] = (b0 + lb + r) * 512 + 64 * w + 4 * l15;  // element index in xrxh[t]
  }
  const int attoff = b0 + lb;

  float hc[2][4];
#pragma unroll
  for (int q = 0; q < 2; q++)
#pragma unroll
    for (int r = 0; r < 4; r++) hc[q][r] = 0.f;

  const f32x4 zz = {0.f, 0.f, 0.f, 0.f};

  auto prefetch = [&](int t) {
    PF pf;
    const unsigned short* xb = xrxh + (size_t)t * 65536;
#pragma unroll
    for (int r = 0; r < 4; r++) pf.x[r] = *(const uint2*)&xb[ro[r]];
    pf.g = *(const f32x4*)&att[t * 128 + attoff];
    return pf;
  };

  auto step = [&](const PF& pf) {
    u16x8 hf[8];
#pragma unroll
    for (int ks = 0; ks < 8; ks++)
      hf[ks] = *(const u16x8*)&hlds[hread + ks * 32];
    f32x4 aA[2] = {zz, zz}, aB[2] = {zz, zz};
#pragma unroll
    for (int ks = 0; ks < 4; ks++)
#pragma unroll
      for (int q = 0; q < 2; q++) {
        aA[q] = mfma16(hf[ks], urf[q][ks], aA[q]);
        aB[q] = mfma16(hf[ks + 4], urf[q][ks + 4], aB[q]);
      }
#pragma unroll
    for (int r = 0; r < 4; r++) {
      const uint2 xv = pf.x[r];
      float s0 = aA[0][r] + aB[0][r] + lo2f(xv.x);
      float s1 = aA[1][r] + aB[1][r] + lo2f(xv.y);
      float rh0 = sigmoid_f(s0) * hc[0][r];
      float rh1 = sigmoid_f(s1) * hc[1][r];
      ((unsigned int*)rhlds)[wdw[r]] = cvtpk(rh0, rh1);
    }
    __syncthreads();
    u16x8 rf[8];
#pragma unroll
    for (int ks = 0; ks < 8; ks++)
      rf[ks] = *(const u16x8*)&rhlds[hread + ks * 32];
    f32x4 bA[2] = {zz, zz}, bB[2] = {zz, zz};
#pragma unroll
    for (int ks = 0; ks < 4; ks++)
#pragma unroll
      for (int q = 0; q < 2; q++) {
        bA[q] = mfma16(rf[ks], uhf[q][ks], bA[q]);
        bB[q] = mfma16(rf[ks + 4], uhf[q][ks + 4], bB[q]);
      }
#pragma unroll
    for (int r = 0; r < 4; r++) {
      const uint2 xv = pf.x[r];
      float ht0 = tanh_f(bA[0][r] + bB[0][r] + hi2f(xv.x));
      float ht1 = tanh_f(bA[1][r] + bB[1][r] + hi2f(xv.y));
      const float g = pf.g[r];
      hc[0][r] = fmaf(g, ht0 - hc[0][r], hc[0][r]);
      hc[1][r] = fmaf(g, ht1 - hc[1][r], hc[1][r]);
      ((unsigned int*)hlds)[wdw[r]] = cvtpk(hc[0][r], hc[1][r]);
    }
    __syncthreads();
  };

  PF cur = prefetch(0);
#pragma unroll 2
  for (int t = 0; t < 512; t++) {
    PF nxt = prefetch(t + 1);  // t=511 reads adjacent ws (allocated, unused)
    step(cur);
    cur = nxt;
  }

  // ===== fused memory update =====
  // cat[16][CPAD]: [0:256) memory (logical), [256:512) episode (storage order),
  //                [512:768) question (logical)
  {
    const int i = (int)threadIdx.x;  // 512 threads: one u16x8 each for mem & q
    const int bb = i >> 5, cc = (i & 31) * 8;
    *(u16x8*)&cat[bb * CPAD + cc] = *(const u16x8*)&mbf[(b0 + bb) * 256 + cc];
    *(u16x8*)&cat[bb * CPAD + 512 + cc] = *(const u16x8*)&qbf[(b0 + bb) * 256 + cc];
  }
#pragma unroll
  for (int r = 0; r < 4; r++) {
    *(unsigned int*)&cat[(lb + r) * CPAD + 256 + 32 * w + 2 * l15] =
        cvtpk(hc[0][r], hc[1][r]);
  }
  __syncthreads();

  f32x4 mA[2] = {zz, zz}, mB[2] = {zz, zz};
#pragma unroll
  for (int ks = 0; ks < 24; ks += 2) {
    u16x8 a0 = *(const u16x8*)&cat[l15 * CPAD + ks * 32 + koff];
    u16x8 a1 = *(const u16x8*)&cat[l15 * CPAD + (ks + 1) * 32 + koff];
#pragma unroll
    for (int q = 0; q < 2; q++) {
      const int vrow = (2 * w + q) * 16 + l15;
      u16x8 bf0 = *(const u16x8*)&memWT[(size_t)vrow * 768 + ks * 32 + koff];
      u16x8 bf1 = *(const u16x8*)&memWT[(size_t)vrow * 768 + (ks + 1) * 32 + koff];
      mA[q] = mfma16(a0, bf0, mA[q]);
      mB[q] = mfma16(a1, bf1, mB[q]);
    }
  }
#pragma unroll
  for (int q = 0; q < 2; q++) {
    const int col = (2 * w + q) * 16 + l15;  // logical v
    const float bv = memb[col];
#pragma unroll
    for (int r = 0; r < 4; r++) {
      float v = fmaxf(mA[q][r] + mB[q][r] + bv, 0.f);
      memory[(size_t)(b0 + lb + r) * 256 + col] = v;
      mbf[(size_t)(b0 + lb + r) * 256 + col] = f2bf(v);
    }
  }
}

__global__ void writeout_kernel(const float* __restrict__ memory,
                                const float* __restrict__ question,
                                float* __restrict__ out) {
  int i = blockIdx.x * 256 + threadIdx.x;  // 65536
  int b = i >> 9, c = i & 511;
  out[i] = (c < 256) ? memory[b * 256 + c] : question[b * 256 + (c - 256)];
}

// ---------------- launch ----------------
extern "C" void kernel_launch(void* const* d_in, const int* in_sizes, int n_in,
                              void* d_out, int out_size, void* d_ws, size_t ws_size,
                              hipStream_t stream) {
  (void)in_sizes; (void)n_in; (void)out_size;
  const float* facts = (const float*)d_in[0];
  const float* question = (const float*)d_in[1];
  const float* l1W = (const float*)d_in[2];
  const float* l1b = (const float*)d_in[3];
  const float* l2W = (const float*)d_in[4];
  const float* Wr = (const float*)d_in[6];
  const float* Ur = (const float*)d_in[7];
  const float* br = (const float*)d_in[8];
  const float* Wh = (const float*)d_in[9];
  const float* Uh = (const float*)d_in[10];
  const float* bh = (const float*)d_in[11];
  const float* memW = (const float*)d_in[12];
  const float* memb = (const float*)d_in[13];
  float* out = (float*)d_out;

  char* ws = (char*)d_ws;
  unsigned short* factsb = (unsigned short*)(ws + 0);          // 33,554,432 B
  unsigned short* xrxh   = (unsigned short*)(ws + 33554432);   // 67,108,864 B [T][B][2U]
  unsigned short* wrT    = (unsigned short*)(ws + 100663296);  // 131,072 B
  unsigned short* whT    = (unsigned short*)(ws + 100794368);
  unsigned short* urT    = (unsigned short*)(ws + 100925440);
  unsigned short* uhT    = (unsigned short*)(ws + 101056512);
  unsigned short* l1qT   = (unsigned short*)(ws + 101187584);  // 524,288 B
  unsigned short* l1mT   = (unsigned short*)(ws + 101711872);  // 524,288 B
  unsigned short* qbf    = (unsigned short*)(ws + 102236160);  // 65,536 B
  unsigned short* mbf    = (unsigned short*)(ws + 102301696);  // 65,536 B
  float* scores          = (float*)(ws + 102367232);           // 262,144 B
  float* att             = (float*)(ws + 102629376);           // 262,144 B
  float* memory          = (float*)(ws + 102891520);           // 131,072 B
  float* brP             = (float*)(ws + 103022592);           // 1,024 B
  float* bhP             = (float*)(ws + 103023616);           // 1,024 B
  unsigned short* memWT  = (unsigned short*)(ws + 103024640);  // 393,216 B
  uint2* accQ            = (uint2*)(ws + 103417856);           // 33,554,432 B
  const bool split = ws_size >= 103417856ull + 33554432ull;    // 136,972,288 B

  cast_facts_kernel<<<2048, 256, 0, stream>>>(facts, factsb, 2097152);
  prep_weights_kernel<<<dim3(256, 7), 256, 0, stream>>>(
      Wr, Wh, Ur, Uh, l1W, br, bh, memW,
      wrT, whT, urT, uhT, l1qT, l1mT, memWT, brP, bhP);
  init_qm_kernel<<<128, 256, 0, stream>>>(question, qbf, mbf);

  gemm_xrxh_kernel<<<1024, 256, 0, stream>>>(factsb, wrT, whT, brP, bhP, xrxh);
  if (split)
    scores_kernel<1><<<512, 256, 0, stream>>>(factsb, l1qT, l1mT, l1b, qbf, mbf,
                                              l2W, scores, accQ);

  for (int step = 0; step < 3; step++) {
    if (split)
      scores_kernel<2><<<512, 256, 0, stream>>>(factsb, l1qT, l1mT, l1b, qbf, mbf,
                                                l2W, scores, accQ);
    else
      scores_kernel<0><<<512, 256, 0, stream>>>(factsb, l1qT, l1mT, l1b, qbf, mbf,
                                                l2W, scores, accQ);
    softmax_kernel<<<128, 64, 0, stream>>>(scores, att);
    scan_kernel<<<8, 512, 0, stream>>>(xrxh, att, urT, uhT, memWT, memb, qbf, mbf, memory);
  }
  writeout_kernel<<<256, 256, 0, stream>>>(memory, question, out);
}

// Round 10
// 2175.813 us; speedup vs baseline: 1.2009x; 1.0311x over previous
//
#include <hip/hip_runtime.h>

// EpisodicMemoryModule: B=128, T=512, U=256, EMB=256, 3 memory hops.
// Round 10: gemm_xrxh B-weights (wrT+whT) staged in LDS per 64-k chunk —
// same L2-BW-bound pattern scores had (R8/R9 verified model: ~10 B/cy/CU on
// scattered b128; staging cuts per-CU traffic 4x). Everything else frozen at
// R9 state (scan at structural LDS-pipe floor ~641 us).

#define DEVI static __device__ __forceinline__

typedef float f32x4 __attribute__((ext_vector_type(4)));
typedef unsigned short u16x8 __attribute__((ext_vector_type(8)));
typedef unsigned int u32x4 __attribute__((ext_vector_type(4)));
typedef __bf16 bf16x8 __attribute__((ext_vector_type(8)));

DEVI f32x4 mfma16(u16x8 a, u16x8 b, f32x4 c) {
  return __builtin_amdgcn_mfma_f32_16x16x32_bf16(
      __builtin_bit_cast(bf16x8, a), __builtin_bit_cast(bf16x8, b), c, 0, 0, 0);
}
DEVI float bf2f(unsigned short u) {
  unsigned int x = ((unsigned int)u) << 16;
  return __builtin_bit_cast(float, x);
}
DEVI float lo2f(unsigned int u) {
  unsigned int x = u << 16;
  return __builtin_bit_cast(float, x);
}
DEVI float hi2f(unsigned int u) {
  unsigned int x = u & 0xffff0000u;
  return __builtin_bit_cast(float, x);
}
DEVI unsigned short f2bf(float f) {
  unsigned int u = __builtin_bit_cast(unsigned int, f);
  return (unsigned short)((u + 0x7fffu + ((u >> 16) & 1u)) >> 16);
}
DEVI unsigned int cvtpk(float lo, float hi) {  // [bf16(lo) | bf16(hi)<<16] RTNE
  unsigned int r;
  asm("v_cvt_pk_bf16_f32 %0, %1, %2" : "=v"(r) : "v"(lo), "v"(hi));
  return r;
}
DEVI float sigmoid_f(float x) {  // inf-safe: rcp(inf)=0
  float e = __expf(-x);
  return __builtin_amdgcn_rcpf(1.f + e);
}
DEVI float tanh_f(float x) {
  float xc = fmaxf(x, -12.f);
  float e = __expf(-2.f * xc);
  return (1.f - e) * __builtin_amdgcn_rcpf(1.f + e);
}
// u-axis storage permutation: s(c) = 32*(c>>5) + 2*(c&15) + ((c>>4)&1)
DEVI int invperm(int s) { return 32 * (s >> 5) + 16 * (s & 1) + ((s & 31) >> 1); }

// ---------------- prep kernels ----------------

__global__ void cast_facts_kernel(const float* __restrict__ in,
                                  unsigned short* __restrict__ out, int n8) {
  int i = blockIdx.x * blockDim.x + threadIdx.x;
  int stride = gridDim.x * blockDim.x;
  for (; i < n8; i += stride) {
    const float4* p = (const float4*)(in + (size_t)i * 8);
    float4 a = p[0], b = p[1];
    u16x8 o;
    o[0] = f2bf(a.x); o[1] = f2bf(a.y); o[2] = f2bf(a.z); o[3] = f2bf(a.w);
    o[4] = f2bf(b.x); o[5] = f2bf(b.y); o[6] = f2bf(b.z); o[7] = f2bf(b.w);
    *(u16x8*)(out + (size_t)i * 8) = o;
  }
}

// z=0/1: wrT/whT[sv][k] = W[k][inv(sv)]  (+ permuted biases at r==0)
// z=2/3: urT/uhT[sv][sk] = U[inv(sk)][inv(sv)]
// z=4/5: l1qT/l1mT (unpermuted, EMB axis)
// z=6:   memWT[v][k] (768 k; episode segment rows permuted to match scan layout)
__global__ void prep_weights_kernel(const float* __restrict__ Wr,
                                    const float* __restrict__ Wh,
                                    const float* __restrict__ Ur,
                                    const float* __restrict__ Uh,
                                    const float* __restrict__ l1W,
                                    const float* __restrict__ br,
                                    const float* __restrict__ bh,
                                    const float* __restrict__ memW,
                                    unsigned short* __restrict__ wrT,
                                    unsigned short* __restrict__ whT,
                                    unsigned short* __restrict__ urT,
                                    unsigned short* __restrict__ uhT,
                                    unsigned short* __restrict__ l1qT,
                                    unsigned short* __restrict__ l1mT,
                                    unsigned short* __restrict__ memWT,
                                    float* __restrict__ brP,
                                    float* __restrict__ bhP) {
  int z = blockIdx.y;
  int r = blockIdx.x;   // output row (storage index for z<4, logical v for z==6)
  int c = threadIdx.x;  // 0..255
  if (z < 2) {
    const float* src = (z == 0) ? Wr : Wh;
    unsigned short* dst = (z == 0) ? wrT : whT;
    dst[r * 256 + c] = f2bf(src[c * 256 + invperm(r)]);
    if (r == 0) {
      if (z == 0) brP[c] = br[invperm(c)];
      else        bhP[c] = bh[invperm(c)];
    }
  } else if (z < 4) {
    const float* src = (z == 2) ? Ur : Uh;
    unsigned short* dst = (z == 2) ? urT : uhT;
    dst[r * 256 + c] = f2bf(src[invperm(c) * 256 + invperm(r)]);
  } else if (z < 6) {
    unsigned short* dst = (z == 4) ? l1qT : l1mT;
    for (int kk = c; kk < 512; kk += 256) {
      int srow;
      if (z == 4) srow = (kk < 256) ? kk : (kk + 256);
      else        srow = (kk < 256) ? (kk + 256) : (kk + 512);
      dst[r * 512 + kk] = f2bf(l1W[srow * 256 + r]);
    }
  } else {  // z == 6
    for (int kk = c; kk < 768; kk += 256) {
      int ksrc = (kk < 256) ? kk : (kk < 512 ? 256 + invperm(kk - 256) : kk);
      memWT[r * 768 + kk] = f2bf(memW[ksrc * 256 + r]);
    }
  }
}

__global__ void init_qm_kernel(const float* __restrict__ question,
                               unsigned short* __restrict__ qbf,
                               unsigned short* __restrict__ mbf) {
  int i = blockIdx.x * 256 + threadIdx.x;  // 32768
  unsigned short u = f2bf(question[i]);
  qbf[i] = u;
  mbf[i] = u;
}

// ---------------- xr/xh GEMM (LDS-staged weights, writes [T][B][2U]) ----------
// Block = 4 waves sharing LDS-staged wrT/whT chunks [256 v][64 k] each
// (pad stride 72 u16 = 36 dw == 4 mod 32, verified-good b128 geometry).
__global__ __launch_bounds__(256, 2) void gemm_xrxh_kernel(
    const unsigned short* __restrict__ factsb,
    const unsigned short* __restrict__ wrT,
    const unsigned short* __restrict__ whT,
    const float* __restrict__ brP, const float* __restrict__ bhP,
    unsigned short* __restrict__ xrxh) {
  __shared__ unsigned short wstg[2][256][72];  // 73,728 B
  const int b = blockIdx.x >> 3;
  const int t0 = (blockIdx.x & 7) * 64;
  const int w = threadIdx.x >> 6, l = threadIdx.x & 63;
  const int l15 = l & 15, lg = l >> 4;
  const int koff = lg * 8;
  const int m0 = t0 + w * 16;
  const int srow = threadIdx.x >> 3;         // 32 staging rows per pass
  const int scol = (threadIdx.x & 7) * 8;    // 8 u16 = 16 B per lane

  f32x4 accR[16], accH[16];
  const f32x4 zz = {0.f, 0.f, 0.f, 0.f};
#pragma unroll
  for (int nt = 0; nt < 16; nt++) { accR[nt] = zz; accH[nt] = zz; }

  const unsigned short* arow = factsb + ((size_t)b * 512 + (m0 + l15)) * 256;

#pragma unroll
  for (int c = 0; c < 4; c++) {  // k-chunk [64c, 64c+64)
    __syncthreads();  // all waves done reading previous chunk
#pragma unroll
    for (int p = 0; p < 8; p++) {  // stage [256][64] x2: coalesced 128B rows
      const int row = p * 32 + srow;
      *(u16x8*)&wstg[0][row][scol] = *(const u16x8*)&wrT[(size_t)row * 256 + c * 64 + scol];
      *(u16x8*)&wstg[1][row][scol] = *(const u16x8*)&whT[(size_t)row * 256 + c * 64 + scol];
    }
    __syncthreads();
#pragma unroll
    for (int ks2 = 0; ks2 < 2; ks2++) {
      const int ks = c * 2 + ks2;
      u16x8 a = *(const u16x8*)&arow[ks * 32 + koff];
#pragma unroll
      for (int nt = 0; nt < 16; nt++) {
        u16x8 bwr = *(const u16x8*)&wstg[0][nt * 16 + l15][ks2 * 32 + koff];
        u16x8 bwh = *(const u16x8*)&wstg[1][nt * 16 + l15][ks2 * 32 + koff];
        accR[nt] = mfma16(a, bwr, accR[nt]);
        accH[nt] = mfma16(a, bwh, accH[nt]);
      }
    }
  }
#pragma unroll
  for (int nt = 0; nt < 16; nt++) {
    const int col = nt * 16 + l15;  // storage col
    const float bvr = brP[col], bvh = bhP[col];
#pragma unroll
    for (int r = 0; r < 4; r++) {
      const int t = m0 + lg * 4 + r;
      unsigned int pk = cvtpk(accR[nt][r] + bvr, accH[nt][r] + bvh);
      *(unsigned int*)&xrxh[((size_t)t * 128 + b) * 512 + col * 2] = pk;
    }
  }
}

// ---------------- attention scores GEMM (LDS-staged B, M=32/wave) -------------
// Block = 4 waves sharing LDS-staged B chunks [256 e][128 k] (pad stride 144).
// SMODE 0: full K=1024 (8 chunks, fallback). SMODE 1: q-half (4 chunks over
// l1qT), store acc frags bf16. SMODE 2: m-half (l1mT) + accQ, tanh epilogue.
template <int SMODE>
__global__ __launch_bounds__(256, 2) void scores_kernel(
    const unsigned short* __restrict__ factsb,
    const unsigned short* __restrict__ l1qT,
    const unsigned short* __restrict__ l1mT,
    const float* __restrict__ l1b,
    const unsigned short* __restrict__ qbf,
    const unsigned short* __restrict__ mbf,
    const float* __restrict__ l2w, float* __restrict__ scores,
    uint2* __restrict__ accQ) {
  __shared__ unsigned short bstg[256][144];  // 73,728 B; stride 36 dw (4 mod 32)
  const int b = blockIdx.x >> 2;
  const int w = threadIdx.x >> 6, l = threadIdx.x & 63;
  const int l15 = l & 15, lg = l >> 4;
  const int koff = lg * 8;
  const int tbase = (blockIdx.x & 3) * 128;
  const int m0 = tbase + w * 16;
  const int fragbase = ((blockIdx.x * 4 + w) * 2) * 16;  // accQ frag index base
  const int srow = threadIdx.x >> 4;          // staging row within 16-row group
  const int scol = (threadIdx.x & 15) * 8;    // staging col (8 u16 = 16 B)

  f32x4 acc[2][16];
  const f32x4 zz = {0.f, 0.f, 0.f, 0.f};
  if constexpr (SMODE == 2) {
#pragma unroll
    for (int s = 0; s < 2; s++)
#pragma unroll
      for (int nt = 0; nt < 16; nt++) {
        uint2 v = accQ[(size_t)(fragbase + s * 16 + nt) * 64 + l];
        acc[s][nt][0] = lo2f(v.x); acc[s][nt][1] = hi2f(v.x);
        acc[s][nt][2] = lo2f(v.y); acc[s][nt][3] = hi2f(v.y);
      }
  } else {
#pragma unroll
    for (int s = 0; s < 2; s++)
#pragma unroll
      for (int nt = 0; nt < 16; nt++) acc[s][nt] = zz;
  }

  const unsigned short* arow0 = factsb + ((size_t)b * 512 + (m0 + l15)) * 256;
  const unsigned short* arow1 = arow0 + 64 * 256;
  const unsigned short* qv = qbf + b * 256;
  const unsigned short* mv = mbf + b * 256;

  const int nc = (SMODE == 0) ? 8 : 4;
#pragma unroll
  for (int c = 0; c < 8; c++) {
    if (c >= nc) break;
    // chunk -> WT selection / transform
    const unsigned short* WTs =
        (SMODE == 1) ? l1qT : (SMODE == 2) ? l1mT : ((c < 4) ? l1qT : l1mT);
    const unsigned short* vvp =
        (SMODE == 1) ? qv : (SMODE == 2) ? mv : ((c < 4) ? qv : mv);
    const int cc = c & 3;                 // col chunk within WT: cols [cc*128,..)
    const bool isabs = (cc >= 2);         // cols >= 256 are the |f-v| quarters
    const unsigned short* WTc = WTs + cc * 128;

    __syncthreads();  // all waves done reading previous chunk
#pragma unroll
    for (int p = 0; p < 16; p++) {        // stage [256][128]: coalesced 16B/lane
      const int row = p * 16 + srow;
      *(u16x8*)&bstg[row][scol] = *(const u16x8*)&WTc[(size_t)row * 512 + scol];
    }
    __syncthreads();

#pragma unroll
    for (int j = 0; j < 4; j++) {
      const int kss = (cc & 1) * 4 + j;   // facts k-group for this chunk col set
      u32x4 f0 = *(const u32x4*)&arow0[kss * 32 + koff];
      u32x4 f1 = *(const u32x4*)&arow1[kss * 32 + koff];
      u32x4 vv = *(const u32x4*)&vvp[kss * 32 + koff];
      u32x4 a0, a1;
#pragma unroll
      for (int jj = 0; jj < 4; jj++) {    // shifted-f32: bf16<<16 is exact f32
        float vl = lo2f(vv[jj]), vh = hi2f(vv[jj]);
        if (isabs) {
          a0[jj] = cvtpk(lo2f(f0[jj]) - vl, hi2f(f0[jj]) - vh) & 0x7fff7fffu;
          a1[jj] = cvtpk(lo2f(f1[jj]) - vl, hi2f(f1[jj]) - vh) & 0x7fff7fffu;
        } else {
          a0[jj] = cvtpk(lo2f(f0[jj]) * vl, hi2f(f0[jj]) * vh);
          a1[jj] = cvtpk(lo2f(f1[jj]) * vl, hi2f(f1[jj]) * vh);
        }
      }
      u16x8 ab0 = __builtin_bit_cast(u16x8, a0);
      u16x8 ab1 = __builtin_bit_cast(u16x8, a1);
#pragma unroll
      for (int nt = 0; nt < 16; nt++) {
        u16x8 bb = *(const u16x8*)&bstg[nt * 16 + l15][j * 32 + koff];
        acc[0][nt] = mfma16(ab0, bb, acc[0][nt]);
        acc[1][nt] = mfma16(ab1, bb, acc[1][nt]);
      }
    }
  }

  if constexpr (SMODE == 1) {
#pragma unroll
    for (int s = 0; s < 2; s++)
#pragma unroll
      for (int nt = 0; nt < 16; nt++) {
        uint2 v;
        v.x = cvtpk(acc[s][nt][0], acc[s][nt][1]);
        v.y = cvtpk(acc[s][nt][2], acc[s][nt][3]);
        accQ[(size_t)(fragbase + s * 16 + nt) * 64 + l] = v;
      }
    return;
  }

  float part[2][4] = {{0.f, 0.f, 0.f, 0.f}, {0.f, 0.f, 0.f, 0.f}};
#pragma unroll
  for (int nt = 0; nt < 16; nt++) {
    const int col = nt * 16 + l15;
    const float lw = l2w[col];
    const float bv = l1b[col];
#pragma unroll
    for (int s = 0; s < 2; s++)
#pragma unroll
      for (int r = 0; r < 4; r++) part[s][r] += tanh_f(acc[s][nt][r] + bv) * lw;
  }
#pragma unroll
  for (int m = 1; m < 16; m <<= 1)
#pragma unroll
    for (int s = 0; s < 2; s++)
#pragma unroll
      for (int r = 0; r < 4; r++) part[s][r] += __shfl_xor(part[s][r], m, 64);
  if (l15 == 0) {
#pragma unroll
    for (int s = 0; s < 2; s++)
#pragma unroll
      for (int r = 0; r < 4; r++)
        scores[(size_t)b * 512 + m0 + s * 64 + lg * 4 + r] = part[s][r];
  }
}

// ---------------- softmax over T per batch ----------------
__global__ void softmax_kernel(const float* __restrict__ scores,
                               float* __restrict__ att) {
  int b = blockIdx.x;
  int l = threadIdx.x;  // 64 threads, 8 scores each
  float v[8];
#pragma unroll
  for (int i = 0; i < 8; i++) v[i] = scores[b * 512 + l * 8 + i];
  float mx = v[0];
#pragma unroll
  for (int i = 1; i < 8; i++) mx = fmaxf(mx, v[i]);
#pragma unroll
  for (int m = 1; m < 64; m <<= 1) mx = fmaxf(mx, __shfl_xor(mx, m, 64));
  float s = 0.f;
#pragma unroll
  for (int i = 0; i < 8; i++) { v[i] = __expf(v[i] - mx); s += v[i]; }
#pragma unroll
  for (int m = 1; m < 64; m <<= 1) s += __shfl_xor(s, m, 64);
  float inv = __builtin_amdgcn_rcpf(s);
#pragma unroll
  for (int i = 0; i < 8; i++) att[(l * 8 + i) * 128 + b] = v[i] * inv;
}

// ---------------- attention-GRU scan + fused memory update ----------------
// 8 blocks x 512 threads (8 waves = 2/SIMD). Block = 16 batches; wave w owns
// storage cols [32w, 32w+32) as an adjacent tile pair (q=0,1). Ur/Uh fragments
// in registers. h in LDS bf16, row stride 132 dwords (==4 mod 32: 4-dword-
// aligned bank starts; odd strides double b128 conflicts — R6 lesson).
struct PF {
  uint2 x[4];  // [r]: .x = (xr|xh<<16) for q=0 col, .y = for q=1 col
  f32x4 g;
};

__global__ __launch_bounds__(512, 2) void scan_kernel(
    const unsigned short* __restrict__ xrxh,   // [T][B][2U] bf16, storage order
    const float* __restrict__ att,             // [T][B]
    const unsigned short* __restrict__ urT,    // [sv][sk] bf16
    const unsigned short* __restrict__ uhT,
    const unsigned short* __restrict__ memWT,  // [v][768] bf16 (episode rows permuted)
    const float* __restrict__ memb,
    const unsigned short* __restrict__ qbf,
    unsigned short* __restrict__ mbf,          // read old memory, write new
    float* __restrict__ memory)                // write new memory f32
{
  constexpr int PAD = 264;   // elements; 528B = 132-dword row stride (4 mod 32)
  constexpr int CPAD = 776;  // cat row stride (768+8)
  __shared__ unsigned short hlds[16 * PAD];
  __shared__ unsigned short rhlds[16 * PAD];
  __shared__ unsigned short cat[16 * CPAD];
  const int w = threadIdx.x >> 6, l = threadIdx.x & 63;
  const int l15 = l & 15, lg = l >> 4;
  const int koff = lg * 8;
  const int b0 = blockIdx.x * 16;
  const int lb = lg * 4;

  // tiles q=0,1: storage col sc = 32w + 2*l15 + q
  u16x8 urf[2][8], uhf[2][8];
#pragma unroll
  for (int q = 0; q < 2; q++) {
    const int sc = 32 * w + 2 * l15 + q;
#pragma unroll
    for (int ks = 0; ks < 8; ks++) {
      urf[q][ks] = *(const u16x8*)&urT[sc * 256 + ks * 32 + koff];
      uhf[q][ks] = *(const u16x8*)&uhT[sc * 256 + ks * 32 + koff];
    }
  }
  for (int i = threadIdx.x; i < 16 * PAD; i += 512) hlds[i] = 0;
  __syncthreads();

  const int hread = l15 * PAD + koff;
  int wdw[4], ro[4];
#pragma unroll
  for (int r = 0; r < 4; r++) {
    wdw[r] = (lb + r) * (PAD / 2) + 16 * w + l15;    // dword index in LDS
    ro[r] = (b0 + lb + r) * 512 + 64 * w + 4 * l15;  // element index in xrxh[t]
  }
  const int attoff = b0 + lb;

  float hc[2][4];
#pragma unroll
  for (int q = 0; q < 2; q++)
#pragma unroll
    for (int r = 0; r < 4; r++) hc[q][r] = 0.f;

  const f32x4 zz = {0.f, 0.f, 0.f, 0.f};

  auto prefetch = [&](int t) {
    PF pf;
    const unsigned short* xb = xrxh + (size_t)t * 65536;
#pragma unroll
    for (int r = 0; r < 4; r++) pf.x[r] = *(const uint2*)&xb[ro[r]];
    pf.g = *(const f32x4*)&att[t * 128 + attoff];
    return pf;
  };

  auto step = [&](const PF& pf) {
    u16x8 hf[8];
#pragma unroll
    for (int ks = 0; ks < 8; ks++)
      hf[ks] = *(const u16x8*)&hlds[hread + ks * 32];
    f32x4 aA[2] = {zz, zz}, aB[2] = {zz, zz};
#pragma unroll
    for (int ks = 0; ks < 4; ks++)
#pragma unroll
      for (int q = 0; q < 2; q++) {
        aA[q] = mfma16(hf[ks], urf[q][ks], aA[q]);
        aB[q] = mfma16(hf[ks + 4], urf[q][ks + 4], aB[q]);
      }
#pragma unroll
    for (int r = 0; r < 4; r++) {
      const uint2 xv = pf.x[r];
      float s0 = aA[0][r] + aB[0][r] + lo2f(xv.x);
      float s1 = aA[1][r] + aB[1][r] + lo2f(xv.y);
      float rh0 = sigmoid_f(s0) * hc[0][r];
      float rh1 = sigmoid_f(s1) * hc[1][r];
      ((unsigned int*)rhlds)[wdw[r]] = cvtpk(rh0, rh1);
    }
    __syncthreads();
    u16x8 rf[8];
#pragma unroll
    for (int ks = 0; ks < 8; ks++)
      rf[ks] = *(const u16x8*)&rhlds[hread + ks * 32];
    f32x4 bA[2] = {zz, zz}, bB[2] = {zz, zz};
#pragma unroll
    for (int ks = 0; ks < 4; ks++)
#pragma unroll
      for (int q = 0; q < 2; q++) {
        bA[q] = mfma16(rf[ks], uhf[q][ks], bA[q]);
        bB[q] = mfma16(rf[ks + 4], uhf[q][ks + 4], bB[q]);
      }
#pragma unroll
    for (int r = 0; r < 4; r++) {
      const uint2 xv = pf.x[r];
      float ht0 = tanh_f(bA[0][r] + bB[0][r] + hi2f(xv.x));
      float ht1 = tanh_f(bA[1][r] + bB[1][r] + hi2f(xv.y));
      const float g = pf.g[r];
      hc[0][r] = fmaf(g, ht0 - hc[0][r], hc[0][r]);
      hc[1][r] = fmaf(g, ht1 - hc[1][r], hc[1][r]);
      ((unsigned int*)hlds)[wdw[r]] = cvtpk(hc[0][r], hc[1][r]);
    }
    __syncthreads();
  };

  PF cur = prefetch(0);
#pragma unroll 2
  for (int t = 0; t < 512; t++) {
    PF nxt = prefetch(t + 1);  // t=511 reads adjacent ws (allocated, unused)
    step(cur);
    cur = nxt;
  }

  // ===== fused memory update =====
  // cat[16][CPAD]: [0:256) memory (logical), [256:512) episode (storage order),
  //                [512:768) question (logical)
  {
    const int i = (int)threadIdx.x;  // 512 threads: one u16x8 each for mem & q
    const int bb = i >> 5, cc = (i & 31) * 8;
    *(u16x8*)&cat[bb * CPAD + cc] = *(const u16x8*)&mbf[(b0 + bb) * 256 + cc];
    *(u16x8*)&cat[bb * CPAD + 512 + cc] = *(const u16x8*)&qbf[(b0 + bb) * 256 + cc];
  }
#pragma unroll
  for (int r = 0; r < 4; r++) {
    *(unsigned int*)&cat[(lb + r) * CPAD + 256 + 32 * w + 2 * l15] =
        cvtpk(hc[0][r], hc[1][r]);
  }
  __syncthreads();

  f32x4 mA[2] = {zz, zz}, mB[2] = {zz, zz};
#pragma unroll
  for (int ks = 0; ks < 24; ks += 2) {
    u16x8 a0 = *(const u16x8*)&cat[l15 * CPAD + ks * 32 + koff];
    u16x8 a1 = *(const u16x8*)&cat[l15 * CPAD + (ks + 1) * 32 + koff];
#pragma unroll
    for (int q = 0; q < 2; q++) {
      const int vrow = (2 * w + q) * 16 + l15;
      u16x8 bf0 = *(const u16x8*)&memWT[(size_t)vrow * 768 + ks * 32 + koff];
      u16x8 bf1 = *(const u16x8*)&memWT[(size_t)vrow * 768 + (ks + 1) * 32 + koff];
      mA[q] = mfma16(a0, bf0, mA[q]);
      mB[q] = mfma16(a1, bf1, mB[q]);
    }
  }
#pragma unroll
  for (int q = 0; q < 2; q++) {
    const int col = (2 * w + q) * 16 + l15;  // logical v
    const float bv = memb[col];
#pragma unroll
    for (int r = 0; r < 4; r++) {
      float v = fmaxf(mA[q][r] + mB[q][r] + bv, 0.f);
      memory[(size_t)(b0 + lb + r) * 256 + col] = v;
      mbf[(size_t)(b0 + lb + r) * 256 + col] = f2bf(v);
    }
  }
}

__global__ void writeout_kernel(const float* __restrict__ memory,
                                const float* __restrict__ question,
                                float* __restrict__ out) {
  int i = blockIdx.x * 256 + threadIdx.x;  // 65536
  int b = i >> 9, c = i & 511;
  out[i] = (c < 256) ? memory[b * 256 + c] : question[b * 256 + (c - 256)];
}

// ---------------- launch ----------------
extern "C" void kernel_launch(void* const* d_in, const int* in_sizes, int n_in,
                              void* d_out, int out_size, void* d_ws, size_t ws_size,
                              hipStream_t stream) {
  (void)in_sizes; (void)n_in; (void)out_size;
  const float* facts = (const float*)d_in[0];
  const float* question = (const float*)d_in[1];
  const float* l1W = (const float*)d_in[2];
  const float* l1b = (const float*)d_in[3];
  const float* l2W = (const float*)d_in[4];
  const float* Wr = (const float*)d_in[6];
  const float* Ur = (const float*)d_in[7];
  const float* br = (const float*)d_in[8];
  const float* Wh = (const float*)d_in[9];
  const float* Uh = (const float*)d_in[10];
  const float* bh = (const float*)d_in[11];
  const float* memW = (const float*)d_in[12];
  const float* memb = (const float*)d_in[13];
  float* out = (float*)d_out;

  char* ws = (char*)d_ws;
  unsigned short* factsb = (unsigned short*)(ws + 0);          // 33,554,432 B
  unsigned short* xrxh   = (unsigned short*)(ws + 33554432);   // 67,108,864 B [T][B][2U]
  unsigned short* wrT    = (unsigned short*)(ws + 100663296);  // 131,072 B
  unsigned short* whT    = (unsigned short*)(ws + 100794368);
  unsigned short* urT    = (unsigned short*)(ws + 100925440);
  unsigned short* uhT    = (unsigned short*)(ws + 101056512);
  unsigned short* l1qT   = (unsigned short*)(ws + 101187584);  // 524,288 B
  unsigned short* l1mT   = (unsigned short*)(ws + 101711872);  // 524,288 B
  unsigned short* qbf    = (unsigned short*)(ws + 102236160);  // 65,536 B
  unsigned short* mbf    = (unsigned short*)(ws + 102301696);  // 65,536 B
  float* scores          = (float*)(ws + 102367232);           // 262,144 B
  float* att             = (float*)(ws + 102629376);           // 262,144 B
  float* memory          = (float*)(ws + 102891520);           // 131,072 B
  float* brP             = (float*)(ws + 103022592);           // 1,024 B
  float* bhP             = (float*)(ws + 103023616);           // 1,024 B
  unsigned short* memWT  = (unsigned short*)(ws + 103024640);  // 393,216 B
  uint2* accQ            = (uint2*)(ws + 103417856);           // 33,554,432 B
  const bool split = ws_size >= 103417856ull + 33554432ull;    // 136,972,288 B

  cast_facts_kernel<<<2048, 256, 0, stream>>>(facts, factsb, 2097152);
  prep_weights_kernel<<<dim3(256, 7), 256, 0, stream>>>(
      Wr, Wh, Ur, Uh, l1W, br, bh, memW,
      wrT, whT, urT, uhT, l1qT, l1mT, memWT, brP, bhP);
  init_qm_kernel<<<128, 256, 0, stream>>>(question, qbf, mbf);

  gemm_xrxh_kernel<<<1024, 256, 0, stream>>>(factsb, wrT, whT, brP, bhP, xrxh);
  if (split)
    scores_kernel<1><<<512, 256, 0, stream>>>(factsb, l1qT, l1mT, l1b, qbf, mbf,
                                              l2W, scores, accQ);

  for (int step = 0; step < 3; step++) {
    if (split)
      scores_kernel<2><<<512, 256, 0, stream>>>(factsb, l1qT, l1mT, l1b, qbf, mbf,
                                                l2W, scores, accQ);
    else
      scores_kernel<0><<<512, 256, 0, stream>>>(factsb, l1qT, l1mT, l1b, qbf, mbf,
                                                l2W, scores, accQ);
    softmax_kernel<<<128, 64, 0, stream>>>(scores, att);
    scan_kernel<<<8, 512, 0, stream>>>(xrxh, att, urT, uhT, memWT, memb, qbf, mbf, memory);
  }
  writeout_kernel<<<256, 256, 0, stream>>>(memory, question, out);
}